// Round 1
// baseline (632.533 us; speedup 1.0000x reference)
//
#include <hip/hip_runtime.h>

// R1: fully-fused fp16-MFMA pipeline.
// prep_k: build L1-normalized Gaussian mix matrices K~ (4 x 64 x 64) in fp16.
// prep_w: cast wm0 to fp16 [80][4096]; zero-pad layer weights to MFMA K/N tiles.
// gauss_main: 1 block = 6 samples. Gauss stack in LDS via mfma_f32_16x16x32_f16
//   (K~ A-frags pinned in registers), h kept in LDS fp16, dense0 = MFMA with
//   4-way K-split streaming wm0-fp16 from L2, dense1 fp32 VALU.
// LDS = 64608 B -> 2 blocks/CU. All matmul accumulation fp32; fp16 inputs give
// ~2e-4 expected absmax (threshold 9.77e-4).

typedef _Float16 f16x8 __attribute__((ext_vector_type(8)));
typedef _Float16 f16x4 __attribute__((ext_vector_type(4)));
typedef float    f32x4 __attribute__((ext_vector_type(4)));

#define GS        6                    // samples per block
#define SLOT_H    4616                 // halves per h/xp slot (64*72 + 8 pad)
#define ACT_H     (GS * SLOT_H)        // 27696 halves: act buffer offset
#define LDS_BYTES ((ACT_H + 64 * 72) * 2)  // 64608 B
// ws layout (halves): [0] wm0 fp16 [80][4096]; then K~, padded weights
#define KT_OFF    327680
#define W0P_OFF   344064               // [16][64], rows>=8 zero
#define W1P_OFF   345088               // [16][32], cols>=8 zero
#define W2P_OFF   345600               // [32][32], cols>=16 zero
#define W3P_OFF   346624               // [64][32]

__global__ void prep_k_kernel(const float* __restrict__ s0, const float* __restrict__ s1,
                              const float* __restrict__ s2, const float* __restrict__ s3,
                              _Float16* __restrict__ kt) {
  int r = threadIdx.x;                 // 256 threads: (layer, row)
  int li = r >> 6, i = r & 63;
  float sg = (li == 0) ? s0[0] : (li == 1) ? s1[0] : (li == 2) ? s2[0] : s3[0];
  float denom = 2.0f * sg * sg;
  float sum = 0.0f;
  for (int j = 0; j < 64; ++j) {
    float d = (float)(i - j);
    sum += expf(-(d * d) / denom);
  }
  float inv = 1.0f / fmaxf(sum, 1e-12f);
  for (int j = 0; j < 64; ++j) {
    float d = (float)(i - j);
    kt[(li * 64 + i) * 64 + j] = (_Float16)(expf(-(d * d) / denom) * inv);
  }
}

__global__ void prep_w_kernel(const float* __restrict__ w0, const float* __restrict__ w1,
                              const float* __restrict__ w2, const float* __restrict__ w3,
                              const float* __restrict__ wm0, _Float16* __restrict__ base) {
  int idx = blockIdx.x * 256 + threadIdx.x;
  if (idx >= 332288) return;
  if (idx < 327680) { base[idx] = (_Float16)wm0[idx]; return; }
  int r = idx - 327680;
  float v;
  if (r < 1024)      { int o = r >> 6, c = r & 63;             v = (o < 8)  ? w0[o * 64 + c] : 0.0f; }
  else if (r < 1536) { int q = r - 1024; int o = q >> 5, c = q & 31; v = (c < 8)  ? w1[o * 8 + c]  : 0.0f; }
  else if (r < 2560) { int q = r - 1536; int o = q >> 5, c = q & 31; v = (c < 16) ? w2[o * 16 + c] : 0.0f; }
  else               { int q = r - 2560; int o = q >> 5, c = q & 31; v = w3[o * 32 + c]; }
  base[344064 + r] = (_Float16)v;
}

__device__ __forceinline__ float leaky(float v) { return v > 0.0f ? v : 0.01f * v; }

// xp[h][o] = sum_c act[h][c] * w[o][c] + b[o]; write xp transposed [o][h] into slot
template<int KCA, int NT, int KPAD>
__device__ __forceinline__ void stage_a(_Float16* lds, const _Float16* wp, const float* bias,
                                        int Cout, int slot, int wv, int lo, int hi) {
#pragma unroll
  for (int nt = 0; nt < NT; ++nt) {
    f32x4 acc = {0.0f, 0.0f, 0.0f, 0.0f};
#pragma unroll
    for (int kc = 0; kc < KCA; ++kc) {
      f16x8 a = *(const f16x8*)(lds + ACT_H + (wv * 16 + lo) * 72 + kc * 32 + hi * 8);
      f16x8 b = *(const f16x8*)(wp + (nt * 16 + lo) * KPAD + kc * 32 + hi * 8);
      acc = __builtin_amdgcn_mfma_f32_16x16x32_f16(a, b, acc, 0, 0, 0);
    }
    int o = nt * 16 + lo;
    float bv = (o < Cout) ? bias[o] : 0.0f;
    f16x4 hv;
#pragma unroll
    for (int r = 0; r < 4; ++r) hv[r] = (_Float16)(acc[r] + bv);
    *(f16x4*)(lds + slot + o * 72 + wv * 16 + hi * 4) = hv;
  }
}

// out[i][o] = leaky(sum_j K~[i][j] * xp[j][o]); write back to act[i][o]
template<int NT>
__device__ __forceinline__ void stage_b(_Float16* lds, const f16x8* kfr, int slot, int wv, int lo, int hi) {
#pragma unroll
  for (int nt = 0; nt < NT; ++nt) {
    f32x4 acc = {0.0f, 0.0f, 0.0f, 0.0f};
#pragma unroll
    for (int kc = 0; kc < 2; ++kc) {
      f16x8 b = *(const f16x8*)(lds + slot + (nt * 16 + lo) * 72 + kc * 32 + hi * 8);
      acc = __builtin_amdgcn_mfma_f32_16x16x32_f16(kfr[kc], b, acc, 0, 0, 0);
    }
    int o = nt * 16 + lo;
#pragma unroll
    for (int r = 0; r < 4; ++r)
      lds[ACT_H + (wv * 16 + hi * 4 + r) * 72 + o] = (_Float16)leaky(acc[r]);
  }
}

__global__ __launch_bounds__(256, 2)
void gauss_main(const float* __restrict__ x,
                const float* __restrict__ bb0, const float* __restrict__ bb1,
                const float* __restrict__ bb2, const float* __restrict__ bb3,
                const float* __restrict__ bm0, const float* __restrict__ wm1,
                const float* __restrict__ bm1,
                const _Float16* __restrict__ wsh,
                float* __restrict__ out, int B) {
  extern __shared__ char smem[];
  _Float16* lds = (_Float16*)smem;
  const int tid = threadIdx.x;
  const int wv = tid >> 6, lane = tid & 63;
  const int lo = lane & 15, hi = lane >> 4;
  const int b0s = blockIdx.x * GS;

  // K~ A-fragments, register-resident for the whole block
  f16x8 kf[4][2];
#pragma unroll
  for (int li = 0; li < 4; ++li)
#pragma unroll
    for (int kc = 0; kc < 2; ++kc)
      kf[li][kc] = *(const f16x8*)(wsh + KT_OFF + (li * 64 + wv * 16 + lo) * 64 + kc * 32 + hi * 8);

  for (int s = 0; s < GS; ++s) {
    const int smp = b0s + s;
    if (smp < B) {
      const float4* xv = (const float4*)(x + (size_t)smp * 4096);
#pragma unroll
      for (int r = 0; r < 4; ++r) {
        float4 v = xv[r * 256 + tid];
        int p = (r * 256 + tid) * 4;
        int h = p >> 6, c = p & 63;
        f16x4 hv;
        hv[0] = (_Float16)v.x; hv[1] = (_Float16)v.y; hv[2] = (_Float16)v.z; hv[3] = (_Float16)v.w;
        *(f16x4*)(lds + ACT_H + h * 72 + c) = hv;
      }
    }
    __syncthreads();
    const int slot = s * SLOT_H;
    stage_a<2, 1, 64>(lds, wsh + W0P_OFF, bb0, 8, slot, wv, lo, hi);
    __syncthreads();
    stage_b<1>(lds, kf[0], slot, wv, lo, hi);
    __syncthreads();
    stage_a<1, 1, 32>(lds, wsh + W1P_OFF, bb1, 16, slot, wv, lo, hi);
    __syncthreads();
    stage_b<1>(lds, kf[1], slot, wv, lo, hi);
    __syncthreads();
    stage_a<1, 2, 32>(lds, wsh + W2P_OFF, bb2, 32, slot, wv, lo, hi);
    __syncthreads();
    stage_b<2>(lds, kf[2], slot, wv, lo, hi);
    __syncthreads();
    stage_a<1, 4, 32>(lds, wsh + W3P_OFF, bb3, 64, slot, wv, lo, hi);
    __syncthreads();
    // L3 stage B writes h into the same slot xp lives in: preload B-frags, sync, then compute+store
    f16x8 pb[8];
#pragma unroll
    for (int nt = 0; nt < 4; ++nt)
#pragma unroll
      for (int kc = 0; kc < 2; ++kc)
        pb[nt * 2 + kc] = *(const f16x8*)(lds + slot + (nt * 16 + lo) * 72 + kc * 32 + hi * 8);
    __syncthreads();
#pragma unroll
    for (int nt = 0; nt < 4; ++nt) {
      f32x4 acc = {0.0f, 0.0f, 0.0f, 0.0f};
      acc = __builtin_amdgcn_mfma_f32_16x16x32_f16(kf[3][0], pb[nt * 2 + 0], acc, 0, 0, 0);
      acc = __builtin_amdgcn_mfma_f32_16x16x32_f16(kf[3][1], pb[nt * 2 + 1], acc, 0, 0, 0);
      int o = nt * 16 + lo;
#pragma unroll
      for (int r = 0; r < 4; ++r)
        lds[slot + (wv * 16 + hi * 4 + r) * 72 + o] = (_Float16)leaky(acc[r]);
    }
  }
  __syncthreads();

  // dense0: C[s][n] = h[s][:4096] . wm0[n][:4096], M=16 (6 used), N=80, 4-way K-split
  f32x4 dacc[5];
#pragma unroll
  for (int nt = 0; nt < 5; ++nt) { f32x4 z = {0.0f, 0.0f, 0.0f, 0.0f}; dacc[nt] = z; }
  const int seff = (lo < GS) ? lo : 0;
  const int kb0 = wv * 1024;
  for (int it = 0; it < 32; ++it) {
    int k = kb0 + it * 32 + hi * 8;
    f16x8 a = *(const f16x8*)(lds + seff * SLOT_H + (k >> 6) * 72 + (k & 63));
#pragma unroll
    for (int nt = 0; nt < 5; ++nt) {
      f16x8 b = *(const f16x8*)(wsh + (size_t)(nt * 16 + lo) * 4096 + k);
      dacc[nt] = __builtin_amdgcn_mfma_f32_16x16x32_f16(a, b, dacc[nt], 0, 0, 0);
    }
  }
  // partial C -> scratch (overlays act buffer; gauss phase is done)
#pragma unroll
  for (int nt = 0; nt < 5; ++nt)
#pragma unroll
    for (int r = 0; r < 4; ++r) {
      int m = hi * 4 + r;
      if (m < 8)
        lds[ACT_H + wv * 640 + m * 80 + nt * 16 + lo] = (_Float16)dacc[nt][r];
    }
  __syncthreads();

  // reduce 4 wave-partials + bias + leaky -> h1 (fp32)
  float* h1 = (float*)(smem + 60512);
  for (int e = tid; e < GS * 80; e += 256) {
    int ss = e / 80, n = e - ss * 80;
    float v = bm0[n];
#pragma unroll
    for (int w = 0; w < 4; ++w) v += (float)lds[ACT_H + w * 640 + ss * 80 + n];
    h1[e] = leaky(v);
  }
  __syncthreads();

  // dense1 fp32 VALU + store
  for (int e = tid; e < GS * 60; e += 256) {
    int ss = e / 60, n = e - ss * 60;
    float v = bm1[n];
    const float* hr = h1 + ss * 80;
    const float* wr = wm1 + n * 80;
#pragma unroll
    for (int k2 = 0; k2 < 80; ++k2) v += hr[k2] * wr[k2];
    int smp = b0s + ss;
    if (smp < B) out[(size_t)smp * 60 + n] = leaky(v);
  }
}

extern "C" void kernel_launch(void* const* d_in, const int* in_sizes, int n_in,
                              void* d_out, int out_size, void* d_ws, size_t ws_size,
                              hipStream_t stream) {
  const float* x   = (const float*)d_in[0];
  const float* w0  = (const float*)d_in[1];
  const float* b0  = (const float*)d_in[2];
  const float* s0  = (const float*)d_in[3];
  const float* w1  = (const float*)d_in[4];
  const float* b1  = (const float*)d_in[5];
  const float* s1  = (const float*)d_in[6];
  const float* w2  = (const float*)d_in[7];
  const float* b2  = (const float*)d_in[8];
  const float* s2  = (const float*)d_in[9];
  const float* w3  = (const float*)d_in[10];
  const float* b3  = (const float*)d_in[11];
  const float* s3  = (const float*)d_in[12];
  const float* wm0 = (const float*)d_in[13];
  const float* bm0 = (const float*)d_in[14];
  const float* wm1 = (const float*)d_in[15];
  const float* bm1 = (const float*)d_in[16];
  float* out = (float*)d_out;
  _Float16* wsh = (_Float16*)d_ws;

  int B = in_sizes[0] / 4096;
  prep_k_kernel<<<1, 256, 0, stream>>>(s0, s1, s2, s3, wsh + KT_OFF);
  prep_w_kernel<<<1298, 256, 0, stream>>>(w0, w1, w2, w3, wm0, wsh);
  int blocks = (B + GS - 1) / GS;
  gauss_main<<<blocks, 256, LDS_BYTES, stream>>>(x, b0, b1, b2, b3, bm0, wm1, bm1, wsh, out, B);
}